// Round 8
// baseline (778.142 us; speedup 1.0000x reference)
//
#include <hip/hip_runtime.h>
#include <hip/hip_fp16.h>

// Regrid, plane-lockstep staged gather + sequential fp16 reduce.
// y[n, b] = sum_{k: rows[k]==b} w[k] * x[n, flip(cols[k])]
// x: (140, 721*1440) f32, rows/cols: (260640,) i32, w: f32, out: (140, 181*360) f32.
//
// Preproc: window(1024-float) hist + row hist -> 2-block scan -> permute:
// perm[j_win] = (cf, w_bits, j_row). Gather: block = one 4KB x-window; loops
// all 140 planes INSIDE the kernel, staging its window slice of each plane
// into LDS with sequential float2 loads (machine sweeps x plane-by-plane in
// lockstep -> DRAM sees sharded-memcpy instead of 581MB-wide random 64B
// permutation), serves its ~257 nnz from LDS, packs 140 fp16 products in
// VGPRs, writes one full 384B g row at the row-sorted slot. Reduce: g read
// fully sequentially, f32 accumulate, LDS transpose, coalesced out stores.

#define NXS 1440
#define NYS 721
#define N_A_CONST (721 * 1440)
#define N_B_CONST (181 * 360)
#define WFL 1024                            // window floats (4KB)
#define NW ((N_A_CONST + WFL - 1) / WFL)    // 1014 windows
#define NFIELD 140
#define NPAIR (NFIELD / 2)                  // 70 plane-pairs
#define GDW 96                              // g row stride in dwords (384B = 3 lines)

__device__ __forceinline__ int flip_col(int c) {
    int iy = c / NXS;
    int ix = c - iy * NXS;
    return (NYS - 1 - iy) * NXS + ix;
}

// ---------- preprocessing ----------

__global__ void zero_ws_kernel(int* __restrict__ p, int n) {
    int i = blockIdx.x * blockDim.x + threadIdx.x;
    int stride = gridDim.x * blockDim.x;
    for (; i < n; i += stride) p[i] = 0;
}

__global__ void hist2_kernel(const int* __restrict__ rows, const int* __restrict__ cols,
                             int* __restrict__ wcount, int* __restrict__ rcount, int nnz) {
    int k = blockIdx.x * blockDim.x + threadIdx.x;
    if (k >= nnz) return;
    int cf = flip_col(cols[k]);
    atomicAdd(&wcount[cf >> 10], 1);
    atomicAdd(&rcount[rows[k]], 1);
}

// block 0: wcount->woff (NW); block 1: rcount->roff (N_B). 1024 thr x 64 elems.
__global__ void scan2_kernel(const int* __restrict__ wcount, int* __restrict__ woff,
                             const int* __restrict__ rcount, int* __restrict__ roff) {
    const int* in; int* out; int n;
    if (blockIdx.x == 0) { in = wcount; out = woff; n = NW; }
    else                 { in = rcount; out = roff; n = N_B_CONST; }

    int t = threadIdx.x;
    int base = t * 64;
    int s = 0;
    for (int i = 0; i < 64; ++i) {
        int idx = base + i;
        s += (idx < n) ? in[idx] : 0;
    }
    int lane = t & 63;
    int wv = t >> 6;
    int incl = s;
    #pragma unroll
    for (int off = 1; off < 64; off <<= 1) {
        int u = __shfl_up(incl, off, 64);
        if (lane >= off) incl += u;
    }
    __shared__ int wsum[16];
    if (lane == 63) wsum[wv] = incl;
    __syncthreads();
    if (t < 16) {
        int v = wsum[t];
        #pragma unroll
        for (int off = 1; off < 16; off <<= 1) {
            int u = __shfl_up(v, off, 16);
            if (t >= off) v += u;
        }
        wsum[t] = v;
    }
    __syncthreads();
    int waveoff = (wv == 0) ? 0 : wsum[wv - 1];
    int run = waveoff + incl - s;
    for (int i = 0; i < 64; ++i) {
        int idx = base + i;
        if (idx < n) { out[idx] = run; run += in[idx]; }
    }
    if (t == 1023) out[n] = run;
}

// perm[j_win] = (cf, w_bits, j_row, 0): j_win window-sorted, j_row row-sorted.
__global__ void perm2_kernel(const int* __restrict__ rows, const int* __restrict__ cols,
                             const float* __restrict__ w,
                             const int* __restrict__ woff, int* __restrict__ wcur,
                             const int* __restrict__ roff, int* __restrict__ rcur,
                             int4* __restrict__ perm, int nnz) {
    int k = blockIdx.x * blockDim.x + threadIdx.x;
    if (k >= nnz) return;
    int cf = flip_col(cols[k]);
    int wu = cf >> 10;
    int j_win = woff[wu] + atomicAdd(&wcur[wu], 1);
    int b = rows[k];
    int j_row = roff[b] + atomicAdd(&rcur[b], 1);
    perm[j_win] = make_int4(cf, __float_as_int(w[k]), j_row, 0);
}

// ---------- hot phases ----------

#define LDPAIR(pp, r0, r1)                                                        \
    {                                                                             \
        int i2 = 2 * tid;                                                         \
        if (i2 < wlim) {                                                          \
            r0 = *(const float2*)&x[(size_t)(2 * (pp)) * N_A_CONST + base + i2];  \
            r1 = *(const float2*)&x[(size_t)(2 * (pp) + 1) * N_A_CONST + base + i2]; \
        } else { r0 = make_float2(0.f, 0.f); r1 = make_float2(0.f, 0.f); }        \
    }

#define STPAIR(buf, r0, r1)                                                       \
    {                                                                             \
        int i2 = 2 * tid;                                                         \
        *(float2*)&sbuf[buf][i2]       = r0;                                      \
        *(float2*)&sbuf[buf][WFL + i2] = r1;                                      \
    }

__global__ __launch_bounds__(512, 4)
void gather_kernel(const float* __restrict__ x, const int4* __restrict__ perm,
                   const int* __restrict__ woff, unsigned int* __restrict__ g) {
    __shared__ float sbuf[2][2 * WFL];      // 2 buffers x 2 planes x 4KB = 16KB
    int wx = blockIdx.x;
    int base = wx * WFL;
    int wlim = N_A_CONST - base; if (wlim > WFL) wlim = WFL;
    int tid = threadIdx.x;
    int j0 = woff[wx], j1 = woff[wx + 1];

    for (int jb = j0; jb < j1; jb += 512) {   // one iteration for this dataset
        bool act = (jb + tid) < j1;
        int4 p = act ? perm[jb + tid] : make_int4(base, 0, 0, 0);
        int cfl = p.x - base;
        float wj = __int_as_float(p.y);
        unsigned int v[NPAIR];

        float2 c0, c1, n0, n1;
        LDPAIR(0, c0, c1);
        STPAIR(0, c0, c1);
        LDPAIR(1, c0, c1);
        __syncthreads();

        #pragma unroll
        for (int pp = 0; pp < NPAIR; ++pp) {
            if (pp + 2 < NPAIR) LDPAIR(pp + 2, n0, n1);
            float b0 = sbuf[pp & 1][cfl];
            float b1 = sbuf[pp & 1][WFL + cfl];
            unsigned int lo = __half_as_ushort(__float2half(wj * b0));
            unsigned int hi = __half_as_ushort(__float2half(wj * b1));
            v[pp] = lo | (hi << 16);
            __syncthreads();
            if (pp + 1 < NPAIR) {
                STPAIR((pp + 1) & 1, c0, c1);
                c0 = n0; c1 = n1;
            }
            __syncthreads();
        }

        if (act) {
            uint4* gp = (uint4*)(g + (size_t)p.z * GDW);
            #pragma unroll
            for (int i = 0; i < 17; ++i)
                gp[i] = make_uint4(v[4 * i], v[4 * i + 1], v[4 * i + 2], v[4 * i + 3]);
            gp[17] = make_uint4(v[68], v[69], 0u, 0u);
            #pragma unroll
            for (int i = 18; i < 24; ++i) gp[i] = make_uint4(0u, 0u, 0u, 0u);
        }
    }
}

__device__ __forceinline__ float h2f_lo(unsigned int d) {
    return __half2float(__ushort_as_half((unsigned short)(d & 0xffffu)));
}
__device__ __forceinline__ float h2f_hi(unsigned int d) {
    return __half2float(__ushort_as_half((unsigned short)(d >> 16)));
}

// Block = 64 rows; g rows for b contiguous -> fully sequential reads.
__global__ __launch_bounds__(256)
void reduce_kernel(const unsigned int* __restrict__ g, const int* __restrict__ roff,
                   float* __restrict__ out) {
    __shared__ float lds[64][141];
    int b0 = blockIdx.x * 64;
    int lane = threadIdx.x & 63;
    int wv = threadIdx.x >> 6;

    for (int i = 0; i < 16; ++i) {
        int bl = wv * 16 + i;
        int b = b0 + bl;
        if (b < N_B_CONST) {
            int p0 = roff[b], p1 = roff[b + 1];
            float a0 = 0.f, a1 = 0.f, a2 = 0.f, a3 = 0.f;
            for (int pos = p0; pos < p1; ++pos) {
                const unsigned int* gr = g + (size_t)pos * GDW;
                unsigned int d = gr[lane];
                a0 += h2f_lo(d); a1 += h2f_hi(d);
                if (lane < 6) {
                    unsigned int e = gr[64 + lane];
                    a2 += h2f_lo(e); a3 += h2f_hi(e);
                }
            }
            lds[bl][2 * lane]     = a0;
            lds[bl][2 * lane + 1] = a1;
            if (lane < 6) {
                lds[bl][128 + 2 * lane] = a2;
                lds[bl][129 + 2 * lane] = a3;
            }
        }
    }
    __syncthreads();

    int nb = N_B_CONST - b0; if (nb > 64) nb = 64;
    for (int idx = threadIdx.x; idx < NFIELD * 64; idx += 256) {
        int f = idx >> 6;
        int rr = idx & 63;
        if (rr < nb)
            out[(size_t)f * N_B_CONST + b0 + rr] = lds[rr][f];
    }
}

// ---------- fallback (only if ws is absurdly small) ----------

__global__ void zero_out_kernel(float* __restrict__ out, int n) {
    int i = blockIdx.x * blockDim.x + threadIdx.x;
    int stride = gridDim.x * blockDim.x;
    for (; i < n; i += stride) out[i] = 0.0f;
}

__global__ void scatter_fallback_kernel(const float* __restrict__ x, const int* __restrict__ rows,
                                        const int* __restrict__ cols, const float* __restrict__ w,
                                        float* __restrict__ out, int nnz) {
    int k = blockIdx.x * blockDim.x + threadIdx.x;
    if (k >= nnz) return;
    int n = blockIdx.y;
    int cf = flip_col(cols[k]);
    float v = w[k] * x[(size_t)n * N_A_CONST + cf];
    atomicAdd(out + (size_t)n * N_B_CONST + rows[k], v);
}

extern "C" void kernel_launch(void* const* d_in, const int* in_sizes, int n_in,
                              void* d_out, int out_size, void* d_ws, size_t ws_size,
                              hipStream_t stream) {
    const float* x    = (const float*)d_in[0];
    const int*   rows = (const int*)d_in[1];
    const int*   cols = (const int*)d_in[2];
    const float* w    = (const float*)d_in[3];
    float* out = (float*)d_out;

    int nnz    = in_sizes[1];
    int nfield = in_sizes[0] / N_A_CONST;   // 140

    // ws layout (int units). Count/cursor arrays first: zeroed by one kernel.
    size_t o = 0;
    size_t wcount_o = o; o += NW;
    size_t wcur_o   = o; o += NW;
    size_t rcount_o = o; o += N_B_CONST;
    size_t rcur_o   = o; o += N_B_CONST;
    size_t zero_span = o;
    size_t woff_o   = o; o += NW + 1;
    size_t roff_o   = o; o += N_B_CONST + 1;
    o = (o + 31) & ~(size_t)31;                 // 128B-align perm
    size_t perm_o   = o; o += 4 * (size_t)nnz;  // int4
    o = (o + 31) & ~(size_t)31;                 // 128B-align g
    size_t g_o      = o;
    size_t need_bytes = (g_o + (size_t)nnz * GDW) * sizeof(int);

    if (ws_size < need_bytes || nfield != NFIELD) {
        zero_out_kernel<<<2048, 256, 0, stream>>>(out, out_size);
        dim3 grid((nnz + 255) / 256, nfield);
        scatter_fallback_kernel<<<grid, 256, 0, stream>>>(x, rows, cols, w, out, nnz);
        return;
    }

    int*  wsI    = (int*)d_ws;
    int*  wcount = wsI + wcount_o;
    int*  wcur   = wsI + wcur_o;
    int*  rcount = wsI + rcount_o;
    int*  rcur   = wsI + rcur_o;
    int*  woff   = wsI + woff_o;
    int*  roff   = wsI + roff_o;
    int4* perm   = (int4*)(wsI + perm_o);
    unsigned int* g = (unsigned int*)(wsI + g_o);

    zero_ws_kernel<<<512, 256, 0, stream>>>(wsI, (int)zero_span);

    int nblk = (nnz + 255) / 256;
    hist2_kernel<<<nblk, 256, 0, stream>>>(rows, cols, wcount, rcount, nnz);
    scan2_kernel<<<2, 1024, 0, stream>>>(wcount, woff, rcount, roff);
    perm2_kernel<<<nblk, 256, 0, stream>>>(rows, cols, w, woff, wcur, roff, rcur, perm, nnz);

    gather_kernel<<<NW, 512, 0, stream>>>(x, perm, woff, g);

    int rblk = (N_B_CONST + 63) / 64;   // 1019
    reduce_kernel<<<rblk, 256, 0, stream>>>(g, roff, out);
}

// Round 9
// 383.749 us; speedup vs baseline: 2.0277x; 2.0277x over previous
//
#include <hip/hip_runtime.h>
#include <hip/hip_fp16.h>

// Regrid, plane-lockstep direct gather + sequential fp16 reduce.
// y[n, b] = sum_{k: rows[k]==b} w[k] * x[n, flip(cols[k])]
// x: (140, 721*1440) f32, rows/cols: (260640,) i32, w: f32, out: (140, 181*360) f32.
//
// Preproc: 64B-line bucket hist + row hist -> 2-block scan -> permute:
// perm[j_cf] = (cf, w_bits, j_row); j_cf cf-line-sorted, j_row row-sorted.
// Gather: block = 256 consecutive cf-sorted nnz (thread = one j); loops all
// 140 planes INSIDE the kernel (2 per iter). Wave's 64 sorted cfs span ~1KB
// -> coalescer merges to full lines; line reuse is same-wave -> L1; all 1019
// blocks sweep planes in lockstep -> HBM sees sharded-memcpy of x (584MB,
// proven round 8). 70 packed fp16 pairs in VGPRs (launch_bounds(256,2):
// 128-VGPR cap, no spill), one full 384B g row written per nnz.
// Reduce: g rows for b contiguous -> fully sequential reads, f32 accumulate,
// LDS transpose, coalesced out stores. No global atomics in hot phases;
// d_out fully overwritten -> no zeroing.

#define NXS 1440
#define NYS 721
#define N_A_CONST (721 * 1440)
#define N_B_CONST (181 * 360)
#define NBUCK (N_A_CONST / 16)     // 64,890 64B-line buckets
#define NFIELD 140
#define NPAIR (NFIELD / 2)         // 70 plane-pairs
#define GDW 96                     // g row stride in dwords (384B = 3 full lines)

__device__ __forceinline__ int flip_col(int c) {
    int iy = c / NXS;
    int ix = c - iy * NXS;
    return (NYS - 1 - iy) * NXS + ix;
}

// ---------- preprocessing ----------

__global__ void zero_ws_kernel(int* __restrict__ p, int n) {
    int i = blockIdx.x * blockDim.x + threadIdx.x;
    int stride = gridDim.x * blockDim.x;
    for (; i < n; i += stride) p[i] = 0;
}

__global__ void hist2_kernel(const int* __restrict__ rows, const int* __restrict__ cols,
                             int* __restrict__ bcount, int* __restrict__ rcount, int nnz) {
    int k = blockIdx.x * blockDim.x + threadIdx.x;
    if (k >= nnz) return;
    int cf = flip_col(cols[k]);
    atomicAdd(&bcount[cf >> 4], 1);
    atomicAdd(&rcount[rows[k]], 1);
}

// block 0: bcount->boff (NBUCK); block 1: rcount->roff (N_B). 1024 thr x 64 elems.
__global__ void scan2_kernel(const int* __restrict__ bcount, int* __restrict__ boff,
                             const int* __restrict__ rcount, int* __restrict__ roff) {
    const int* in; int* out; int n;
    if (blockIdx.x == 0) { in = bcount; out = boff; n = NBUCK; }
    else                 { in = rcount; out = roff; n = N_B_CONST; }

    int t = threadIdx.x;
    int base = t * 64;
    int s = 0;
    for (int i = 0; i < 64; ++i) {
        int idx = base + i;
        s += (idx < n) ? in[idx] : 0;
    }
    int lane = t & 63;
    int wv = t >> 6;
    int incl = s;
    #pragma unroll
    for (int off = 1; off < 64; off <<= 1) {
        int u = __shfl_up(incl, off, 64);
        if (lane >= off) incl += u;
    }
    __shared__ int wsum[16];
    if (lane == 63) wsum[wv] = incl;
    __syncthreads();
    if (t < 16) {
        int v = wsum[t];
        #pragma unroll
        for (int off = 1; off < 16; off <<= 1) {
            int u = __shfl_up(v, off, 16);
            if (t >= off) v += u;
        }
        wsum[t] = v;
    }
    __syncthreads();
    int waveoff = (wv == 0) ? 0 : wsum[wv - 1];
    int run = waveoff + incl - s;
    for (int i = 0; i < 64; ++i) {
        int idx = base + i;
        if (idx < n) { out[idx] = run; run += in[idx]; }
    }
    if (t == 1023) out[n] = run;
}

// perm[j_cf] = (cf, w_bits, j_row, 0)
__global__ void perm2_kernel(const int* __restrict__ rows, const int* __restrict__ cols,
                             const float* __restrict__ w,
                             const int* __restrict__ boff, int* __restrict__ bcur,
                             const int* __restrict__ roff, int* __restrict__ rcur,
                             int4* __restrict__ perm, int nnz) {
    int k = blockIdx.x * blockDim.x + threadIdx.x;
    if (k >= nnz) return;
    int cf = flip_col(cols[k]);
    int bu = cf >> 4;
    int j_cf = boff[bu] + atomicAdd(&bcur[bu], 1);
    int b = rows[k];
    int j_row = roff[b] + atomicAdd(&rcur[b], 1);
    perm[j_cf] = make_int4(cf, __float_as_int(w[k]), j_row, 0);
}

// ---------- hot phases ----------

__global__ __launch_bounds__(256, 2)
void gather_kernel(const float* __restrict__ x, const int4* __restrict__ perm,
                   unsigned int* __restrict__ g, int nnz) {
    int j = blockIdx.x * 256 + (int)threadIdx.x;
    bool act = j < nnz;
    int4 p = perm[act ? j : (nnz - 1)];
    const float* xp = x + p.x;
    float wj = __int_as_float(p.y);

    unsigned int v[NPAIR];
    #pragma unroll
    for (int pp = 0; pp < NPAIR; ++pp) {
        float f0 = xp[(size_t)(2 * pp) * N_A_CONST];
        float f1 = xp[(size_t)(2 * pp + 1) * N_A_CONST];
        unsigned int lo = __half_as_ushort(__float2half(wj * f0));
        unsigned int hi = __half_as_ushort(__float2half(wj * f1));
        v[pp] = lo | (hi << 16);
    }

    if (act) {
        uint4* gp = (uint4*)(g + (size_t)p.z * GDW);
        #pragma unroll
        for (int i = 0; i < 17; ++i)
            gp[i] = make_uint4(v[4 * i], v[4 * i + 1], v[4 * i + 2], v[4 * i + 3]);
        gp[17] = make_uint4(v[68], v[69], 0u, 0u);
        #pragma unroll
        for (int i = 18; i < 24; ++i) gp[i] = make_uint4(0u, 0u, 0u, 0u);  // full-line writes
    }
}

__device__ __forceinline__ float h2f_lo(unsigned int d) {
    return __half2float(__ushort_as_half((unsigned short)(d & 0xffffu)));
}
__device__ __forceinline__ float h2f_hi(unsigned int d) {
    return __half2float(__ushort_as_half((unsigned short)(d >> 16)));
}

// Block = 64 rows; g rows for b contiguous -> fully sequential reads.
__global__ __launch_bounds__(256)
void reduce_kernel(const unsigned int* __restrict__ g, const int* __restrict__ roff,
                   float* __restrict__ out) {
    __shared__ float lds[64][141];
    int b0 = blockIdx.x * 64;
    int lane = threadIdx.x & 63;
    int wv = threadIdx.x >> 6;

    for (int i = 0; i < 16; ++i) {
        int bl = wv * 16 + i;
        int b = b0 + bl;
        if (b < N_B_CONST) {
            int p0 = roff[b], p1 = roff[b + 1];
            float a0 = 0.f, a1 = 0.f, a2 = 0.f, a3 = 0.f;
            for (int pos = p0; pos < p1; ++pos) {
                const unsigned int* gr = g + (size_t)pos * GDW;
                unsigned int d = gr[lane];
                a0 += h2f_lo(d); a1 += h2f_hi(d);
                if (lane < 6) {
                    unsigned int e = gr[64 + lane];
                    a2 += h2f_lo(e); a3 += h2f_hi(e);
                }
            }
            lds[bl][2 * lane]     = a0;
            lds[bl][2 * lane + 1] = a1;
            if (lane < 6) {
                lds[bl][128 + 2 * lane] = a2;
                lds[bl][129 + 2 * lane] = a3;
            }
        }
    }
    __syncthreads();

    int nb = N_B_CONST - b0; if (nb > 64) nb = 64;
    for (int idx = threadIdx.x; idx < NFIELD * 64; idx += 256) {
        int f = idx >> 6;
        int rr = idx & 63;
        if (rr < nb)
            out[(size_t)f * N_B_CONST + b0 + rr] = lds[rr][f];
    }
}

// ---------- fallback ----------

__global__ void zero_out_kernel(float* __restrict__ out, int n) {
    int i = blockIdx.x * blockDim.x + threadIdx.x;
    int stride = gridDim.x * blockDim.x;
    for (; i < n; i += stride) out[i] = 0.0f;
}

__global__ void scatter_fallback_kernel(const float* __restrict__ x, const int* __restrict__ rows,
                                        const int* __restrict__ cols, const float* __restrict__ w,
                                        float* __restrict__ out, int nnz) {
    int k = blockIdx.x * blockDim.x + threadIdx.x;
    if (k >= nnz) return;
    int n = blockIdx.y;
    int cf = flip_col(cols[k]);
    float v = w[k] * x[(size_t)n * N_A_CONST + cf];
    atomicAdd(out + (size_t)n * N_B_CONST + rows[k], v);
}

extern "C" void kernel_launch(void* const* d_in, const int* in_sizes, int n_in,
                              void* d_out, int out_size, void* d_ws, size_t ws_size,
                              hipStream_t stream) {
    const float* x    = (const float*)d_in[0];
    const int*   rows = (const int*)d_in[1];
    const int*   cols = (const int*)d_in[2];
    const float* w    = (const float*)d_in[3];
    float* out = (float*)d_out;

    int nnz    = in_sizes[1];
    int nfield = in_sizes[0] / N_A_CONST;   // 140

    // ws layout (int units). Count/cursor arrays first: zeroed by one kernel.
    size_t o = 0;
    size_t bcount_o = o; o += NBUCK;
    size_t bcur_o   = o; o += NBUCK;
    size_t rcount_o = o; o += N_B_CONST;
    size_t rcur_o   = o; o += N_B_CONST;
    size_t zero_span = o;
    size_t boff_o   = o; o += NBUCK + 1;
    size_t roff_o   = o; o += N_B_CONST + 1;
    o = (o + 31) & ~(size_t)31;                 // 128B-align perm
    size_t perm_o   = o; o += 4 * (size_t)nnz;  // int4
    o = (o + 31) & ~(size_t)31;                 // 128B-align g
    size_t g_o      = o;
    size_t need_bytes = (g_o + (size_t)nnz * GDW) * sizeof(int);

    if (ws_size < need_bytes || nfield != NFIELD) {
        zero_out_kernel<<<2048, 256, 0, stream>>>(out, out_size);
        dim3 grid((nnz + 255) / 256, nfield);
        scatter_fallback_kernel<<<grid, 256, 0, stream>>>(x, rows, cols, w, out, nnz);
        return;
    }

    int*  wsI    = (int*)d_ws;
    int*  bcount = wsI + bcount_o;
    int*  bcur   = wsI + bcur_o;
    int*  rcount = wsI + rcount_o;
    int*  rcur   = wsI + rcur_o;
    int*  boff   = wsI + boff_o;
    int*  roff   = wsI + roff_o;
    int4* perm   = (int4*)(wsI + perm_o);
    unsigned int* g = (unsigned int*)(wsI + g_o);

    zero_ws_kernel<<<512, 256, 0, stream>>>(wsI, (int)zero_span);

    int nblk = (nnz + 255) / 256;   // 1019
    hist2_kernel<<<nblk, 256, 0, stream>>>(rows, cols, bcount, rcount, nnz);
    scan2_kernel<<<2, 1024, 0, stream>>>(bcount, boff, rcount, roff);
    perm2_kernel<<<nblk, 256, 0, stream>>>(rows, cols, w, boff, bcur, roff, rcur, perm, nnz);

    gather_kernel<<<nblk, 256, 0, stream>>>(x, perm, g, nnz);

    int rblk = (N_B_CONST + 63) / 64;   // 1019
    reduce_kernel<<<rblk, 256, 0, stream>>>(g, roff, out);
}